// Round 1
// baseline (223.304 us; speedup 1.0000x reference)
//
#include <hip/hip_runtime.h>

// out[b, c] = x[b, c] * diag[c]   for x:(8192, 4096) fp32, diag:(4096,) fp32.
// Pure memory-bound streaming kernel: float4 per lane, fully coalesced.

#define SIZE 4096
#define SIZE4 (SIZE / 4)          // 1024, power of two -> mask for column index
#define N_ELEM (8192 * SIZE)
#define N4 (N_ELEM / 4)           // 8,388,608 float4 groups

__global__ __launch_bounds__(256) void diag_scale_kernel(
    const float4* __restrict__ x,
    const float4* __restrict__ d,
    float4* __restrict__ out)
{
    const int i = blockIdx.x * blockDim.x + threadIdx.x;  // grid sized exactly
    const float4 xv = x[i];
    const float4 dv = d[i & (SIZE4 - 1)];
    float4 r;
    r.x = xv.x * dv.x;
    r.y = xv.y * dv.y;
    r.z = xv.z * dv.z;
    r.w = xv.w * dv.w;
    out[i] = r;
}

extern "C" void kernel_launch(void* const* d_in, const int* in_sizes, int n_in,
                              void* d_out, int out_size, void* d_ws, size_t ws_size,
                              hipStream_t stream)
{
    const float4* x = (const float4*)d_in[0];   // (8192, 4096) fp32
    const float4* d = (const float4*)d_in[1];   // (4096,) fp32
    float4* out = (float4*)d_out;               // (8192, 4096) fp32

    const int block = 256;
    const int grid = N4 / block;                // 32768 blocks, exact cover
    diag_scale_kernel<<<grid, block, 0, stream>>>(x, d, out);
}